// Round 6
// baseline (761.067 us; speedup 1.0000x reference)
//
#include <hip/hip_runtime.h>

typedef unsigned short ushort_t;
typedef __attribute__((ext_vector_type(8))) __bf16 bf16x8;
typedef __attribute__((ext_vector_type(4))) float f32x4;

#define SEQ 8192
#define DIN 1024
#define DOUT 1024

// epilogue output modes
#define OM_BF16 0
#define OM_F32  1
#define OM_EXP  2   // bf16 exp2(scale*acc) store + per-block partial row-sums -> rsp
#define OM_NORM 3   // f32 store of acc * invrs[row] (precomputed 1/rowsum)

__device__ __forceinline__ ushort_t f2bf(float f) {
  union { float f; unsigned u; } c; c.f = f;
  unsigned u = c.u;
  return (ushort_t)((u + 0x7fffu + ((u >> 16) & 1u)) >> 16);  // RNE
}

__device__ __forceinline__ void async16(ushort_t* lds, const ushort_t* g) {
  __builtin_amdgcn_global_load_lds(
      (__attribute__((address_space(1))) void*)g,
      (__attribute__((address_space(3))) void*)lds, 16, 0, 0);
}

// ------- fused fp32 -> bf16 convert for x, Wq, Wk, Wv -------
__global__ __launch_bounds__(256) void cvt_all_kernel(
    const float* __restrict__ x, const float* __restrict__ wq,
    const float* __restrict__ wk, const float* __restrict__ wv,
    ushort_t* __restrict__ xb, ushort_t* __restrict__ wqkb,
    ushort_t* __restrict__ wvb) {
  int b = blockIdx.x;
  const float* src;
  ushort_t* dst;
  int idx;
  if (b < 8192) {
    src = x; dst = xb; idx = b * 256 + threadIdx.x;
  } else {
    int r = b - 8192;
    int w = r >> 10;
    idx = (r & 1023) * 256 + threadIdx.x;
    if (w == 0)      { src = wq; dst = wqkb; }
    else if (w == 1) { src = wk; dst = wqkb + DOUT * DIN; }
    else             { src = wv; dst = wvb; }
  }
  float4 f = ((const float4*)src)[idx];
  ushort4 o;
  o.x = f2bf(f.x); o.y = f2bf(f.y); o.z = f2bf(f.z); o.w = f2bf(f.w);
  ((ushort4*)dst)[idx] = o;
}

// ------- rowsum partials [64][SEQ] -> invrs[SEQ] = 1/sum -------
__global__ __launch_bounds__(256) void rowsum_inv_kernel(const float* __restrict__ rsp,
                                                         float* __restrict__ invrs) {
  int r = blockIdx.x * 256 + threadIdx.x;
  float s = 0.f;
  #pragma unroll
  for (int p2 = 0; p2 < 64; ++p2) s += rsp[p2 * SEQ + r];
  invrs[r] = 1.0f / s;
}

// ---------------- GEMM: C[M][N] = A[M][K] @ B[N][K]^T ----------------
// 128x128 tile, templated BK (64/128), 4 waves (2x2), each wave 64x64 via 4x4
// mfma_f32_16x16x32_bf16.
//
// FRAGMENT-ORDERED LDS (round-6 change): tile stored as 16B slots
//   s = (ks*8 + panel)*64 + lane,  lane <-> (row = panel*16 + (lane&15),
//                                            k   = ks*32 + (lane>>4)*8)
// which is exactly the 16x16x32 A/B fragment mapping. Consequences:
//  - fragment read = LDS base + lane*16 + constexpr offset -> ds_read_b128
//    with immediate offset, ZERO per-fragment VALU, ZERO bank conflicts
//    (64 lanes read 64 consecutive 16B slots).
//  - global side of global_load_lds carries the scatter (per-lane global
//    addresses are unconstrained; only the LDS side must be lane-linear).
//  - staging addresses: per-thread pointers precomputed once, bumped by BK
//    per kt (round-5 profile: VALUBusy 55% vs MfmaUtil 34% -> K-loop was
//    VALU-co-bound on address math).
// BK=128 halves barrier drains — only where occupancy is grid-limited to 2/CU
// anyway (PV, vT). SWZ=1: 8 blocks sharing an A-strip on one XCD (4x FETCH cut).
// OM_EXP: store exp2(scale*acc) bf16 (scale carries log2e); partial row-sums
//   via shuffle+LDS, PLAIN store to rsp[nt][row] (no atomics: round-4 showed
//   1M atomicAdds onto 8K addresses = ~40 us stall).
// OM_NORM: normalize by precomputed invrs[row] (reduction moved to its own
//   tiny kernel; round-5 showed the in-epilogue 64-partial loop cost ~10 us).
template <int OUTMODE, int SWZ, int BK>
__global__ __launch_bounds__(256) void gemm_bt(const ushort_t* __restrict__ A,
                                               const ushort_t* __restrict__ B,
                                               void* __restrict__ C,
                                               int lda, int ldb, int ldc,
                                               int K, float scale,
                                               float* __restrict__ rsp,
                                               const float* __restrict__ invrs) {
  constexpr int NI = BK / 16;           // staging iterations (slots/thread)
  __shared__ ushort_t As[128 * BK];
  __shared__ ushort_t Bs[128 * BK];
  const int t = threadIdx.x;
  const int lane = t & 63;
  const int wave = t >> 6;
  const int wr = wave >> 1, wc = wave & 1;
  const int quad = lane >> 4, r16 = lane & 15;

  int mt, nt;
  if (SWZ == 1) {
    mt = blockIdx.x * (gridDim.y >> 3) + (blockIdx.y >> 3);
    nt = blockIdx.y & 7;
  } else {
    mt = blockIdx.y;
    nt = blockIdx.x;
  }
  const int rowBase = mt * 128;
  const int colBase = nt * 128;

  // per-thread staging source pointers (bumped by BK per kt)
  const ushort_t* gA[NI];
  const ushort_t* gB[NI];
  #pragma unroll
  for (int i = 0; i < NI; ++i) {
    int s = t + i * 256;
    int ks = s >> 9;                 // 512 slots per ks-group
    int pnl = (s >> 6) & 7;
    int l = s & 63;
    int row = pnl * 16 + (l & 15);
    int kk = ks * 32 + ((l >> 4) & 3) * 8;
    gA[i] = A + (size_t)(rowBase + row) * lda + kk;
    gB[i] = B + (size_t)(colBase + row) * ldb + kk;
  }

  f32x4 acc[4][4] = {};

  const int nk = K / BK;
  for (int kt = 0; kt < nk; ++kt) {
    #pragma unroll
    for (int i = 0; i < NI; ++i) {
      async16(&As[(t + i * 256) * 8], gA[i]); gA[i] += BK;
      async16(&Bs[(t + i * 256) * 8], gB[i]); gB[i] += BK;
    }
    __syncthreads();
    #pragma unroll
    for (int ks = 0; ks < BK / 32; ++ks) {
      bf16x8 af[4], bfr[4];
      #pragma unroll
      for (int mi = 0; mi < 4; ++mi)
        af[mi] = *(const bf16x8*)&As[((ks * 8 + wr * 4 + mi) << 9) + lane * 8];
      #pragma unroll
      for (int ni = 0; ni < 4; ++ni)
        bfr[ni] = *(const bf16x8*)&Bs[((ks * 8 + wc * 4 + ni) << 9) + lane * 8];
      #pragma unroll
      for (int mi = 0; mi < 4; ++mi)
        #pragma unroll
        for (int ni = 0; ni < 4; ++ni)
          acc[mi][ni] = __builtin_amdgcn_mfma_f32_16x16x32_bf16(af[mi], bfr[ni],
                                                                acc[mi][ni], 0, 0, 0);
    }
    __syncthreads();
  }

  // ---- epilogue: C/D layout col=lane&15, row=quad*4+reg ----
  float iv[4][4];
  if (OUTMODE == OM_NORM) {
    #pragma unroll
    for (int mi = 0; mi < 4; ++mi)
      #pragma unroll
      for (int r = 0; r < 4; ++r)
        iv[mi][r] = invrs[rowBase + wr * 64 + mi * 16 + quad * 4 + r];
  }

  float psum[4][4];
  if (OUTMODE == OM_EXP) {
    #pragma unroll
    for (int mi = 0; mi < 4; ++mi)
      #pragma unroll
      for (int r = 0; r < 4; ++r) psum[mi][r] = 0.f;
  }

  #pragma unroll
  for (int mi = 0; mi < 4; ++mi)
    #pragma unroll
    for (int ni = 0; ni < 4; ++ni)
      #pragma unroll
      for (int r = 0; r < 4; ++r) {
        int grow = rowBase + wr * 64 + mi * 16 + quad * 4 + r;
        int gcol = colBase + wc * 64 + ni * 16 + r16;
        float a = acc[mi][ni][r];
        if (OUTMODE == OM_F32) {
          ((float*)C)[(size_t)grow * ldc + gcol] = a * scale;
        } else if (OUTMODE == OM_BF16) {
          ((ushort_t*)C)[(size_t)grow * ldc + gcol] = f2bf(a * scale);
        } else if (OUTMODE == OM_EXP) {
          float e = exp2f(a * scale);   // scale carries the log2(e) factor
          psum[mi][r] += e;
          ((ushort_t*)C)[(size_t)grow * ldc + gcol] = f2bf(e);
        } else {  // OM_NORM
          ((float*)C)[(size_t)grow * ldc + gcol] = a * iv[mi][r];
        }
      }

  if (OUTMODE == OM_EXP) {
    // 16-lane shuffle reduce -> lane r16==0 holds this wave's 64-col partial
    float* lds_rs = (float*)As;  // [2][128], LDS dead after final barrier
    #pragma unroll
    for (int mi = 0; mi < 4; ++mi)
      #pragma unroll
      for (int r = 0; r < 4; ++r) {
        float s = psum[mi][r];
        s += __shfl_xor(s, 1, 64);
        s += __shfl_xor(s, 2, 64);
        s += __shfl_xor(s, 4, 64);
        s += __shfl_xor(s, 8, 64);
        if (r16 == 0)
          lds_rs[wc * 128 + wr * 64 + mi * 16 + quad * 4 + r] = s;
      }
    __syncthreads();
    if (t < 128)
      rsp[(size_t)nt * SEQ + rowBase + t] = lds_rs[t] + lds_rs[128 + t];
  }
}

extern "C" void kernel_launch(void* const* d_in, const int* in_sizes, int n_in,
                              void* d_out, int out_size, void* d_ws, size_t ws_size,
                              hipStream_t stream) {
  const float* x  = (const float*)d_in[0];
  const float* Wq = (const float*)d_in[1];
  const float* Wk = (const float*)d_in[2];
  const float* Wv = (const float*)d_in[3];
  float* out = (float*)d_out;

  char* p = (char*)d_ws;
  ushort_t* xb   = (ushort_t*)p; p += (size_t)SEQ * DIN * 2;        // 16 MB
  ushort_t* wqkb = (ushort_t*)p; p += (size_t)2 * DOUT * DIN * 2;   //  4 MB (Wq|Wk)
  ushort_t* wvb  = (ushort_t*)p; p += (size_t)DOUT * DIN * 2;       //  2 MB
  ushort_t* qkb  = (ushort_t*)p; p += (size_t)SEQ * 2 * DOUT * 2;   // 32 MB ([S][2048], q|k)
  ushort_t* vtb  = (ushort_t*)p; p += (size_t)DOUT * SEQ * 2;       // 16 MB (v^T)
  float*    rsp  = (float*)p;    p += (size_t)64 * SEQ * 4;         //  2 MB partial rowsums
  float*    irs  = (float*)p;    p += (size_t)SEQ * 4;              // 32 KB 1/rowsum
  ushort_t* Sb   = (ushort_t*)p; p += (size_t)SEQ * SEQ * 2;        // 128 MB

  // fp32 -> bf16 for all four tensors (one launch)
  cvt_all_kernel<<<8192 + 3 * 1024, 256, 0, stream>>>(x, Wq, Wk, Wv, xb, wqkb, wvb);

  dim3 blk(256);
  // [q|k] = x @ [Wq|Wk]^T : M=8192, N=2048, K=1024
  gemm_bt<OM_BF16, 0, 64><<<dim3(2048 / 128, SEQ / 128), blk, 0, stream>>>(
      xb, wqkb, qkb, DIN, DIN, 2 * DOUT, DIN, 1.0f, nullptr, nullptr);

  // v^T = Wv @ x^T : M=1024, N=8192, K=1024 (512 blocks = 2/CU grid-limited -> BK=128)
  gemm_bt<OM_BF16, 0, 128><<<dim3(SEQ / 128, DOUT / 128), blk, 0, stream>>>(
      wvb, xb, vtb, DIN, DIN, SEQ, DIN, 1.0f, nullptr, nullptr);

  // E = exp((q @ k^T)/32) via exp2, partial row sums -> rsp : M=N=8192, K=1024
  gemm_bt<OM_EXP, 0, 64><<<dim3(SEQ / 128, SEQ / 128), blk, 0, stream>>>(
      qkb, qkb + DOUT, Sb, 2 * DOUT, 2 * DOUT, SEQ, DIN,
      0.03125f * 1.44269504f, rsp, nullptr);

  // invrs[r] = 1 / sum_p rsp[p][r]
  rowsum_inv_kernel<<<SEQ / 256, blk, 0, stream>>>(rsp, irs);

  // out = (E @ v) * invrs : M=8192, N=1024, K=8192, fp32 out, XCD-swizzled, BK=128
  gemm_bt<OM_NORM, 1, 128><<<dim3(DOUT / 128, SEQ / 128), blk, 0, stream>>>(
      Sb, vtb, out, SEQ, SEQ, DOUT, SEQ, 1.0f, nullptr, irs);
}

// Round 7
// 478.027 us; speedup vs baseline: 1.5921x; 1.5921x over previous
//
#include <hip/hip_runtime.h>

typedef unsigned short ushort_t;
typedef __attribute__((ext_vector_type(8))) __bf16 bf16x8;
typedef __attribute__((ext_vector_type(4))) float f32x4;

#define SEQ 8192
#define DIN 1024
#define DOUT 1024

// epilogue output modes
#define OM_BF16 0
#define OM_F32  1
#define OM_EXP  2   // bf16 exp2(scale*acc) store + per-block partial row-sums -> rsp
#define OM_NORM 3   // f32 store of acc * invrs[row] (precomputed 1/rowsum)

__device__ __forceinline__ ushort_t f2bf(float f) {
  union { float f; unsigned u; } c; c.f = f;
  unsigned u = c.u;
  return (ushort_t)((u + 0x7fffu + ((u >> 16) & 1u)) >> 16);  // RNE
}

__device__ __forceinline__ void async16(ushort_t* lds, const ushort_t* g) {
  __builtin_amdgcn_global_load_lds(
      (__attribute__((address_space(1))) void*)g,
      (__attribute__((address_space(3))) void*)lds, 16, 0, 0);
}

// ------- fused fp32 -> bf16 convert for x, Wq, Wk, Wv -------
__global__ __launch_bounds__(256) void cvt_all_kernel(
    const float* __restrict__ x, const float* __restrict__ wq,
    const float* __restrict__ wk, const float* __restrict__ wv,
    ushort_t* __restrict__ xb, ushort_t* __restrict__ wqkb,
    ushort_t* __restrict__ wvb) {
  int b = blockIdx.x;
  const float* src;
  ushort_t* dst;
  int idx;
  if (b < 8192) {
    src = x; dst = xb; idx = b * 256 + threadIdx.x;
  } else {
    int r = b - 8192;
    int w = r >> 10;
    idx = (r & 1023) * 256 + threadIdx.x;
    if (w == 0)      { src = wq; dst = wqkb; }
    else if (w == 1) { src = wk; dst = wqkb + DOUT * DIN; }
    else             { src = wv; dst = wvb; }
  }
  float4 f = ((const float4*)src)[idx];
  ushort4 o;
  o.x = f2bf(f.x); o.y = f2bf(f.y); o.z = f2bf(f.z); o.w = f2bf(f.w);
  ((ushort4*)dst)[idx] = o;
}

// ------- rowsum partials [64][SEQ] -> invrs[SEQ] = 1/sum -------
__global__ __launch_bounds__(256) void rowsum_inv_kernel(const float* __restrict__ rsp,
                                                         float* __restrict__ invrs) {
  int r = blockIdx.x * 256 + threadIdx.x;
  float s = 0.f;
  #pragma unroll
  for (int p2 = 0; p2 < 64; ++p2) s += rsp[p2 * SEQ + r];
  invrs[r] = 1.0f / s;
}

// ---------------- GEMM: C[M][N] = A[M][K] @ B[N][K]^T ----------------
// 128x128 tile, templated BK (64/128), 4 waves (2x2), each wave 64x64 via 4x4
// mfma_f32_16x16x32_bf16. Round-5 proven layout: XOR-swizzled row-major LDS
// (16B chunk low3 ^ row&7) — conflict-free ds_read_b128, swizzle on the GLOBAL
// source address so global_load_lds lane-contiguity holds, and the wave's
// global accesses stay in full contiguous 128B/256B row segments.
// *** round-6 lesson: do NOT scatter the global side (fragment-ordered LDS
// put 16x 64B stride-16KB segments per instruction -> 2x regression). ***
// Round-7 change: staging source offsets are kt-invariant + kt*BK, so hold
// per-thread 32-bit element offsets and bump by BK per kt (saddr-form loads,
// 1 v_add each) instead of recomputing 64-bit addresses (round-5 VALUBusy 55%).
// BK=128 halves barrier drains — only where occupancy is grid-limited to 2/CU
// anyway (PV, vT). SWZ=1: 8 blocks sharing an A-strip on one XCD (4x FETCH cut).
// OM_EXP: store exp2(scale*acc) bf16 (scale carries log2e); partial row-sums
//   via shuffle+LDS, PLAIN store to rsp[nt][row] (no atomics: round-4 showed
//   1M atomicAdds onto 8K addresses = ~40 us stall).
// OM_NORM: normalize by precomputed invrs[row] (tiny separate kernel).
template <int OUTMODE, int SWZ, int BK>
__global__ __launch_bounds__(256) void gemm_bt(const ushort_t* __restrict__ A,
                                               const ushort_t* __restrict__ B,
                                               void* __restrict__ C,
                                               int lda, int ldb, int ldc,
                                               int K, float scale,
                                               float* __restrict__ rsp,
                                               const float* __restrict__ invrs) {
  constexpr int CPR = BK / 8;           // 16B chunks per row
  constexpr int NI = BK / 16;           // staging chunks per thread
  __shared__ ushort_t As[128 * BK];
  __shared__ ushort_t Bs[128 * BK];
  const int t = threadIdx.x;
  const int lane = t & 63;
  const int wave = t >> 6;
  const int wr = wave >> 1, wc = wave & 1;
  const int quad = lane >> 4, r16 = lane & 15;

  int mt, nt;
  if (SWZ == 1) {
    mt = blockIdx.x * (gridDim.y >> 3) + (blockIdx.y >> 3);
    nt = blockIdx.y & 7;
  } else {
    mt = blockIdx.y;
    nt = blockIdx.x;
  }
  const int rowBase = mt * 128;
  const int colBase = nt * 128;

  // per-thread 32-bit staging offsets (elements), bumped by BK per kt
  unsigned offA[NI], offB[NI];
  #pragma unroll
  for (int i = 0; i < NI; ++i) {
    int c = t + i * 256;
    int row = c / CPR;
    int kq = c & (CPR - 1);
    int kqs = (kq & ~7) | ((kq & 7) ^ (row & 7));
    offA[i] = (unsigned)((rowBase + row) * lda + kqs * 8);
    offB[i] = (unsigned)((colBase + row) * ldb + kqs * 8);
  }

  f32x4 acc[4][4] = {};

  const int nk = K / BK;
  for (int kt = 0; kt < nk; ++kt) {
    #pragma unroll
    for (int i = 0; i < NI; ++i) {
      async16(&As[(t + i * 256) * 8], A + offA[i]); offA[i] += BK;
      async16(&Bs[(t + i * 256) * 8], B + offB[i]); offB[i] += BK;
    }
    __syncthreads();
    #pragma unroll
    for (int ks = 0; ks < BK / 32; ++ks) {
      bf16x8 af[4], bfr[4];
      #pragma unroll
      for (int mi = 0; mi < 4; ++mi) {
        int row = wr * 64 + mi * 16 + r16;
        int kq = ks * 4 + quad;
        int c = row * CPR + ((kq & ~7) | ((kq & 7) ^ (row & 7)));
        af[mi] = *(const bf16x8*)&As[c * 8];
      }
      #pragma unroll
      for (int ni = 0; ni < 4; ++ni) {
        int row = wc * 64 + ni * 16 + r16;
        int kq = ks * 4 + quad;
        int c = row * CPR + ((kq & ~7) | ((kq & 7) ^ (row & 7)));
        bfr[ni] = *(const bf16x8*)&Bs[c * 8];
      }
      #pragma unroll
      for (int mi = 0; mi < 4; ++mi)
        #pragma unroll
        for (int ni = 0; ni < 4; ++ni)
          acc[mi][ni] = __builtin_amdgcn_mfma_f32_16x16x32_bf16(af[mi], bfr[ni],
                                                                acc[mi][ni], 0, 0, 0);
    }
    __syncthreads();
  }

  // ---- epilogue: C/D layout col=lane&15, row=quad*4+reg ----
  float iv[4][4];
  if (OUTMODE == OM_NORM) {
    #pragma unroll
    for (int mi = 0; mi < 4; ++mi)
      #pragma unroll
      for (int r = 0; r < 4; ++r)
        iv[mi][r] = invrs[rowBase + wr * 64 + mi * 16 + quad * 4 + r];
  }

  float psum[4][4];
  if (OUTMODE == OM_EXP) {
    #pragma unroll
    for (int mi = 0; mi < 4; ++mi)
      #pragma unroll
      for (int r = 0; r < 4; ++r) psum[mi][r] = 0.f;
  }

  #pragma unroll
  for (int mi = 0; mi < 4; ++mi)
    #pragma unroll
    for (int ni = 0; ni < 4; ++ni)
      #pragma unroll
      for (int r = 0; r < 4; ++r) {
        int grow = rowBase + wr * 64 + mi * 16 + quad * 4 + r;
        int gcol = colBase + wc * 64 + ni * 16 + r16;
        float a = acc[mi][ni][r];
        if (OUTMODE == OM_F32) {
          ((float*)C)[(size_t)grow * ldc + gcol] = a * scale;
        } else if (OUTMODE == OM_BF16) {
          ((ushort_t*)C)[(size_t)grow * ldc + gcol] = f2bf(a * scale);
        } else if (OUTMODE == OM_EXP) {
          float e = exp2f(a * scale);   // scale carries the log2(e) factor
          psum[mi][r] += e;
          ((ushort_t*)C)[(size_t)grow * ldc + gcol] = f2bf(e);
        } else {  // OM_NORM
          ((float*)C)[(size_t)grow * ldc + gcol] = a * iv[mi][r];
        }
      }

  if (OUTMODE == OM_EXP) {
    // 16-lane shuffle reduce -> lane r16==0 holds this wave's 64-col partial
    float* lds_rs = (float*)As;  // [2][128], LDS dead after final barrier
    #pragma unroll
    for (int mi = 0; mi < 4; ++mi)
      #pragma unroll
      for (int r = 0; r < 4; ++r) {
        float s = psum[mi][r];
        s += __shfl_xor(s, 1, 64);
        s += __shfl_xor(s, 2, 64);
        s += __shfl_xor(s, 4, 64);
        s += __shfl_xor(s, 8, 64);
        if (r16 == 0)
          lds_rs[wc * 128 + wr * 64 + mi * 16 + quad * 4 + r] = s;
      }
    __syncthreads();
    if (t < 128)
      rsp[(size_t)nt * SEQ + rowBase + t] = lds_rs[t] + lds_rs[128 + t];
  }
}

extern "C" void kernel_launch(void* const* d_in, const int* in_sizes, int n_in,
                              void* d_out, int out_size, void* d_ws, size_t ws_size,
                              hipStream_t stream) {
  const float* x  = (const float*)d_in[0];
  const float* Wq = (const float*)d_in[1];
  const float* Wk = (const float*)d_in[2];
  const float* Wv = (const float*)d_in[3];
  float* out = (float*)d_out;

  char* p = (char*)d_ws;
  ushort_t* xb   = (ushort_t*)p; p += (size_t)SEQ * DIN * 2;        // 16 MB
  ushort_t* wqkb = (ushort_t*)p; p += (size_t)2 * DOUT * DIN * 2;   //  4 MB (Wq|Wk)
  ushort_t* wvb  = (ushort_t*)p; p += (size_t)DOUT * DIN * 2;       //  2 MB
  ushort_t* qkb  = (ushort_t*)p; p += (size_t)SEQ * 2 * DOUT * 2;   // 32 MB ([S][2048], q|k)
  ushort_t* vtb  = (ushort_t*)p; p += (size_t)DOUT * SEQ * 2;       // 16 MB (v^T)
  float*    rsp  = (float*)p;    p += (size_t)64 * SEQ * 4;         //  2 MB partial rowsums
  float*    irs  = (float*)p;    p += (size_t)SEQ * 4;              // 32 KB 1/rowsum
  ushort_t* Sb   = (ushort_t*)p; p += (size_t)SEQ * SEQ * 2;        // 128 MB

  // fp32 -> bf16 for all four tensors (one launch)
  cvt_all_kernel<<<8192 + 3 * 1024, 256, 0, stream>>>(x, Wq, Wk, Wv, xb, wqkb, wvb);

  dim3 blk(256);
  // [q|k] = x @ [Wq|Wk]^T : M=8192, N=2048, K=1024
  gemm_bt<OM_BF16, 0, 64><<<dim3(2048 / 128, SEQ / 128), blk, 0, stream>>>(
      xb, wqkb, qkb, DIN, DIN, 2 * DOUT, DIN, 1.0f, nullptr, nullptr);

  // v^T = Wv @ x^T : M=1024, N=8192, K=1024 (512 blocks = 2/CU grid-limited -> BK=128)
  gemm_bt<OM_BF16, 0, 128><<<dim3(SEQ / 128, DOUT / 128), blk, 0, stream>>>(
      wvb, xb, vtb, DIN, DIN, SEQ, DIN, 1.0f, nullptr, nullptr);

  // E = exp((q @ k^T)/32) via exp2, partial row sums -> rsp : M=N=8192, K=1024
  gemm_bt<OM_EXP, 0, 64><<<dim3(SEQ / 128, SEQ / 128), blk, 0, stream>>>(
      qkb, qkb + DOUT, Sb, 2 * DOUT, 2 * DOUT, SEQ, DIN,
      0.03125f * 1.44269504f, rsp, nullptr);

  // invrs[r] = 1 / sum_p rsp[p][r]
  rowsum_inv_kernel<<<SEQ / 256, blk, 0, stream>>>(rsp, irs);

  // out = (E @ v) * invrs : M=8192, N=1024, K=8192, fp32 out, XCD-swizzled, BK=128
  gemm_bt<OM_NORM, 1, 128><<<dim3(DOUT / 128, SEQ / 128), blk, 0, stream>>>(
      Sb, vtb, out, SEQ, SEQ, DOUT, SEQ, 1.0f, nullptr, irs);
}